// Round 3
// baseline (480.988 us; speedup 1.0000x reference)
//
#include <hip/hip_runtime.h>
#include <stdint.h>

#define NN 8192
#define INC 256
#define OUTC 64
#define LOG2E 1.4426950408889634f

typedef __bf16 bf16x8 __attribute__((ext_vector_type(8)));
typedef float f32x4 __attribute__((ext_vector_type(4)));

__device__ __forceinline__ unsigned short f2bf(float x) {
    union { float f; unsigned u; } v; v.f = x;
    unsigned u = v.u;
    u += 0x7fffu + ((u >> 16) & 1u);   // RNE, inputs never NaN
    return (unsigned short)(u >> 16);
}

#if __has_builtin(__builtin_amdgcn_exp2f)
#define EXP2(x) __builtin_amdgcn_exp2f(x)
#else
#define EXP2(x) exp2f(x)
#endif

// K1: per 16-row block: Wh -> WhTf (MFMA-B-frag interleaved bf16) + Wh1[i] + Wh2[i]
__global__ __launch_bounds__(256) void gat_k1(
        const float* __restrict__ h, const float* __restrict__ W,
        const float* __restrict__ a,
        unsigned short* __restrict__ WhTf, float* __restrict__ Wh1,
        float* __restrict__ Wh2) {
    __shared__ float Ws[256 * 65];          // 65 KB, padded (conflict-free both phases)
    __shared__ float hs[16 * INC];          // 16 KB
    __shared__ float Wa1s[256], Wa2s[256], as_[128];
    __shared__ unsigned short wt[OUTC][16]; // transpose buffer
    const int r0 = blockIdx.x * 16;
    const int t  = threadIdx.x;
    if (t < 128) as_[t] = a[t];
    #pragma unroll
    for (int it = 0; it < 16; ++it) {
        int idx = it * 1024 + t * 4;        // flat index into W
        float4 v = *reinterpret_cast<const float4*>(W + idx);
        int k = idx >> 6, c = idx & 63;
        float* dst = &Ws[k * 65 + c];
        dst[0] = v.x; dst[1] = v.y; dst[2] = v.z; dst[3] = v.w;
    }
    #pragma unroll
    for (int it = 0; it < 4; ++it) {
        int idx = it * 1024 + t * 4;
        float4 v = *reinterpret_cast<const float4*>(h + (size_t)r0 * INC + idx);
        hs[idx] = v.x; hs[idx + 1] = v.y; hs[idx + 2] = v.z; hs[idx + 3] = v.w;
    }
    __syncthreads();
    {
        float s1 = 0.f, s2 = 0.f;
        #pragma unroll 8
        for (int c = 0; c < OUTC; ++c) {
            float w = Ws[t * 65 + c];
            s1 = fmaf(w, as_[c], s1);
            s2 = fmaf(w, as_[OUTC + c], s2);
        }
        Wa1s[t] = s1; Wa2s[t] = s2;
    }
    __syncthreads();
    const int w = t >> 6, lane = t & 63;
    const int c = lane;
    const float* hr = &hs[w * 4 * INC];
    float acc0 = 0.f, acc1 = 0.f, acc2 = 0.f, acc3 = 0.f;
    #pragma unroll 8
    for (int k = 0; k < INC; ++k) {
        float wv = Ws[k * 65 + c];
        acc0 = fmaf(hr[k],           wv, acc0);
        acc1 = fmaf(hr[INC + k],     wv, acc1);
        acc2 = fmaf(hr[2 * INC + k], wv, acc2);
        acc3 = fmaf(hr[3 * INC + k], wv, acc3);
    }
    float s1r[4] = {0.f, 0.f, 0.f, 0.f}, s2r[4] = {0.f, 0.f, 0.f, 0.f};
    #pragma unroll
    for (int kk = 0; kk < 4; ++kk) {
        int k = kk * 64 + lane;
        float wa1v = Wa1s[k], wa2v = Wa2s[k];
        #pragma unroll
        for (int r = 0; r < 4; ++r) {
            float hv = hr[r * INC + k];
            s1r[r] = fmaf(hv, wa1v, s1r[r]);
            s2r[r] = fmaf(hv, wa2v, s2r[r]);
        }
    }
    #pragma unroll
    for (int r = 0; r < 4; ++r) {
        float s1 = s1r[r], s2 = s2r[r];
        #pragma unroll
        for (int off = 32; off; off >>= 1) {
            s1 += __shfl_xor(s1, off, 64);
            s2 += __shfl_xor(s2, off, 64);
        }
        if (lane == 0) { Wh1[r0 + w * 4 + r] = s1; Wh2[r0 + w * 4 + r] = s2; }
    }
    wt[c][w * 4 + 0] = f2bf(acc0);
    wt[c][w * 4 + 1] = f2bf(acc1);
    wt[c][w * 4 + 2] = f2bf(acc2);
    wt[c][w * 4 + 3] = f2bf(acc3);
    __syncthreads();
    // WhTf frag layout: base (( (j>>5)*4 + (c>>4) )<<9) + ( ((j>>3)&3)*16 + (c&15) )*8 + (j&7)
    if (t < 128) {
        int m = t & 15, ct = (t >> 4) & 3, oct = t >> 6;
        int Kb = r0 >> 5;
        int qh = (r0 >> 3) & 3;              // 0 or 2
        int lanef = (qh + oct) * 16 + m;
        int cidx = ct * 16 + m;
        ushort4 v0, v1;
        v0.x = wt[cidx][oct * 8 + 0]; v0.y = wt[cidx][oct * 8 + 1];
        v0.z = wt[cidx][oct * 8 + 2]; v0.w = wt[cidx][oct * 8 + 3];
        v1.x = wt[cidx][oct * 8 + 4]; v1.y = wt[cidx][oct * 8 + 5];
        v1.z = wt[cidx][oct * 8 + 6]; v1.w = wt[cidx][oct * 8 + 7];
        unsigned short* dst = WhTf + (((size_t)(Kb * 4 + ct)) << 9) + lanef * 8;
        *reinterpret_cast<ushort4*>(dst)     = v0;
        *reinterpret_cast<ushort4*>(dst + 4) = v1;
    }
}

// K2: M = max(Wh2)
__global__ void gat_k2(const float* __restrict__ Wh2, float* __restrict__ M) {
    __shared__ float red[16];
    int t = threadIdx.x;  // 1024
    float4 v0 = *reinterpret_cast<const float4*>(Wh2 + t * 4);
    float4 v1 = *reinterpret_cast<const float4*>(Wh2 + 4096 + t * 4);
    float m = fmaxf(fmaxf(fmaxf(v0.x, v0.y), fmaxf(v0.z, v0.w)),
                    fmaxf(fmaxf(v1.x, v1.y), fmaxf(v1.z, v1.w)));
    #pragma unroll
    for (int off = 32; off; off >>= 1) m = fmaxf(m, __shfl_xor(m, off, 64));
    if ((t & 63) == 0) red[t >> 6] = m;
    __syncthreads();
    if (t == 0) {
        float mm = red[0];
        #pragma unroll
        for (int i = 1; i < 16; ++i) mm = fmaxf(mm, red[i]);
        *M = mm;
    }
}

// K3: 512 blocks x 256 threads (4 waves); 16 rows/block; 32 j per wave-iter;
// adj prefetch distance 2; Wh2 from global (L1-hot); 16.3 KB LDS -> high occupancy.
__global__ __launch_bounds__(256, 5) void gat_k3(
        const int* __restrict__ adj, const unsigned short* __restrict__ WhTf,
        const float* __restrict__ Wh1, const float* __restrict__ Wh2,
        const float* __restrict__ Mp, float* __restrict__ out) {
    __shared__ float accs[4][16 * OUTC]; // 16 KB
    __shared__ float ls[4][16];
    const int r0 = blockIdx.x * 16;
    const int t = threadIdx.x;
    const int w = t >> 6, lane = t & 63;
    const int m = lane & 15, q = lane >> 4;
    const int qo = q * 8;
    const int row = r0 + m;
    const float wh1 = Wh1[row];
    const float Mv = *Mp;
    const float sM = wh1 + Mv;
    const float mhat = fmaxf(sM, 0.5f * sM);   // leaky(wh1 + max Wh2) >= row max
    const float mh2 = mhat * LOG2E;
    const int* __restrict__ arow = adj + (size_t)row * NN;
    f32x4 acc[4] = {{0,0,0,0},{0,0,0,0},{0,0,0,0},{0,0,0,0}};
    float lpart = 0.f;

    // software pipeline: adj prefetched 2 iterations ahead
    int4 c0 = *reinterpret_cast<const int4*>(arow + (size_t)w * 32 + qo);
    int4 c1 = *reinterpret_cast<const int4*>(arow + (size_t)w * 32 + qo + 4);
    int4 d0 = *reinterpret_cast<const int4*>(arow + (size_t)(w + 4) * 32 + qo);
    int4 d1 = *reinterpret_cast<const int4*>(arow + (size_t)(w + 4) * 32 + qo + 4);

    #pragma unroll 2
    for (int i = 0; i < 64; ++i) {
        const int jt = w + i * 4;
        // 1) B-fragments (L2-hot, fully coalesced 16 B/lane)
        const unsigned short* fb = WhTf + (size_t)jt * 2048 + lane * 8;
        bf16x8 bv0 = *reinterpret_cast<const bf16x8*>(fb);
        bf16x8 bv1 = *reinterpret_cast<const bf16x8*>(fb + 512);
        bf16x8 bv2 = *reinterpret_cast<const bf16x8*>(fb + 1024);
        bf16x8 bv3 = *reinterpret_cast<const bf16x8*>(fb + 1536);
        // 2) Wh2 (L1-hot)
        const int jb = jt * 32 + qo;
        float4 s0 = *reinterpret_cast<const float4*>(Wh2 + jb);
        float4 s1 = *reinterpret_cast<const float4*>(Wh2 + jb + 4);
        // 3) adj prefetch for i+2 (issued last -> stays in flight past the s-wait)
        const int jn = (i < 62) ? (jt + 8) : w;
        const int* __restrict__ an = arow + (size_t)jn * 32 + qo;
        int4 e0 = *reinterpret_cast<const int4*>(an);
        int4 e1 = *reinterpret_cast<const int4*>(an + 4);
        // 4) p from current adj (loaded 2 iters ago) + Wh2
        float sv[8] = {s0.x, s0.y, s0.z, s0.w, s1.x, s1.y, s1.z, s1.w};
        int   av[8] = {c0.x, c0.y, c0.z, c0.w, c1.x, c1.y, c1.z, c1.w};
        float p[8];
        #pragma unroll
        for (int e = 0; e < 8; ++e) {
            float s  = wh1 + sv[e];
            float lk = fmaxf(s, 0.5f * s);        // leakyrelu(0.5)
            float ar = fmaf(lk, LOG2E, -mh2);
            float pe = EXP2(ar);
            p[e] = (av[e] > 0) ? pe : 0.f;
        }
        lpart += ((p[0] + p[1]) + (p[2] + p[3])) + ((p[4] + p[5]) + (p[6] + p[7]));
        bf16x8 af;
        #pragma unroll
        for (int e = 0; e < 8; ++e) af[e] = (__bf16)p[e];
        // 5) MFMA (waits bv only; adj prefetch stays outstanding)
        acc[0] = __builtin_amdgcn_mfma_f32_16x16x32_bf16(af, bv0, acc[0], 0, 0, 0);
        acc[1] = __builtin_amdgcn_mfma_f32_16x16x32_bf16(af, bv1, acc[1], 0, 0, 0);
        acc[2] = __builtin_amdgcn_mfma_f32_16x16x32_bf16(af, bv2, acc[2], 0, 0, 0);
        acc[3] = __builtin_amdgcn_mfma_f32_16x16x32_bf16(af, bv3, acc[3], 0, 0, 0);
        c0 = d0; c1 = d1; d0 = e0; d1 = e1;
    }
    // dump accumulators: C/D layout col=lane&15, row=q*4+reg
    #pragma unroll
    for (int ct = 0; ct < 4; ++ct)
        #pragma unroll
        for (int r = 0; r < 4; ++r)
            accs[w][(q * 4 + r) * OUTC + ct * 16 + m] = acc[ct][r];
    float l = lpart;
    l += __shfl_xor(l, 16, 64);
    l += __shfl_xor(l, 32, 64);
    if (lane < 16) ls[w][lane] = l;
    __syncthreads();
    #pragma unroll
    for (int e = t; e < 16 * OUTC; e += 256) {
        int rr = e >> 6, cc = e & 63;
        float s = (accs[0][e] + accs[1][e]) + (accs[2][e] + accs[3][e]);
        float lsum = (ls[0][rr] + ls[1][rr]) + (ls[2][rr] + ls[3][rr]);
        float o = s / lsum;
        out[(size_t)(r0 + rr) * OUTC + cc] = o > 0.f ? o : 0.f;
    }
}

extern "C" void kernel_launch(void* const* d_in, const int* in_sizes, int n_in,
                              void* d_out, int out_size, void* d_ws, size_t ws_size,
                              hipStream_t stream) {
    const float* h   = (const float*)d_in[0];
    const int*   adj = (const int*)d_in[1];
    const float* W   = (const float*)d_in[2];
    const float* a   = (const float*)d_in[3];
    float* out = (float*)d_out;

    char* base = (char*)d_ws;
    float* Wh1 = (float*)(base);                 // 8192 f @ 0
    float* Wh2 = (float*)(base + 32768);         // 8192 f @ 32 KB
    float* Mp  = (float*)(base + 65536);         // 1 f
    unsigned short* WhTf = (unsigned short*)(base + 69632); // 64*8192 bf16 = 1 MB

    gat_k1<<<NN / 16, 256, 0, stream>>>(h, W, a, WhTf, Wh1, Wh2);
    gat_k2<<<1, 1024, 0, stream>>>(Wh2, Mp);
    gat_k3<<<NN / 16, 256, 0, stream>>>(adj, WhTf, Wh1, Wh2, Mp, out);
}

// Round 4
// 426.391 us; speedup vs baseline: 1.1280x; 1.1280x over previous
//
#include <hip/hip_runtime.h>
#include <stdint.h>

#define NN 8192
#define INC 256
#define OUTC 64
#define LOG2E 1.4426950408889634f
#define JSPLIT 4

typedef __bf16 bf16x8 __attribute__((ext_vector_type(8)));
typedef float f32x4 __attribute__((ext_vector_type(4)));

__device__ __forceinline__ unsigned short f2bf(float x) {
    union { float f; unsigned u; } v; v.f = x;
    unsigned u = v.u;
    u += 0x7fffu + ((u >> 16) & 1u);   // RNE, inputs never NaN
    return (unsigned short)(u >> 16);
}

#if __has_builtin(__builtin_amdgcn_exp2f)
#define EXP2(x) __builtin_amdgcn_exp2f(x)
#else
#define EXP2(x) exp2f(x)
#endif

// K1: per 16-row block: Wh -> WhTf (MFMA-B-frag interleaved bf16) + Wh1[i] + Wh2[i]
__global__ __launch_bounds__(256) void gat_k1(
        const float* __restrict__ h, const float* __restrict__ W,
        const float* __restrict__ a,
        unsigned short* __restrict__ WhTf, float* __restrict__ Wh1,
        float* __restrict__ Wh2) {
    __shared__ float Ws[256 * 65];          // 65 KB, padded (conflict-free both phases)
    __shared__ float hs[16 * INC];          // 16 KB
    __shared__ float Wa1s[256], Wa2s[256], as_[128];
    __shared__ unsigned short wt[OUTC][16]; // transpose buffer
    const int r0 = blockIdx.x * 16;
    const int t  = threadIdx.x;
    if (t < 128) as_[t] = a[t];
    #pragma unroll
    for (int it = 0; it < 16; ++it) {
        int idx = it * 1024 + t * 4;        // flat index into W
        float4 v = *reinterpret_cast<const float4*>(W + idx);
        int k = idx >> 6, c = idx & 63;
        float* dst = &Ws[k * 65 + c];
        dst[0] = v.x; dst[1] = v.y; dst[2] = v.z; dst[3] = v.w;
    }
    #pragma unroll
    for (int it = 0; it < 4; ++it) {
        int idx = it * 1024 + t * 4;
        float4 v = *reinterpret_cast<const float4*>(h + (size_t)r0 * INC + idx);
        hs[idx] = v.x; hs[idx + 1] = v.y; hs[idx + 2] = v.z; hs[idx + 3] = v.w;
    }
    __syncthreads();
    {
        float s1 = 0.f, s2 = 0.f;
        #pragma unroll 8
        for (int c = 0; c < OUTC; ++c) {
            float w = Ws[t * 65 + c];
            s1 = fmaf(w, as_[c], s1);
            s2 = fmaf(w, as_[OUTC + c], s2);
        }
        Wa1s[t] = s1; Wa2s[t] = s2;
    }
    __syncthreads();
    const int w = t >> 6, lane = t & 63;
    const int c = lane;
    const float* hr = &hs[w * 4 * INC];
    float acc0 = 0.f, acc1 = 0.f, acc2 = 0.f, acc3 = 0.f;
    #pragma unroll 8
    for (int k = 0; k < INC; ++k) {
        float wv = Ws[k * 65 + c];
        acc0 = fmaf(hr[k],           wv, acc0);
        acc1 = fmaf(hr[INC + k],     wv, acc1);
        acc2 = fmaf(hr[2 * INC + k], wv, acc2);
        acc3 = fmaf(hr[3 * INC + k], wv, acc3);
    }
    float s1r[4] = {0.f, 0.f, 0.f, 0.f}, s2r[4] = {0.f, 0.f, 0.f, 0.f};
    #pragma unroll
    for (int kk = 0; kk < 4; ++kk) {
        int k = kk * 64 + lane;
        float wa1v = Wa1s[k], wa2v = Wa2s[k];
        #pragma unroll
        for (int r = 0; r < 4; ++r) {
            float hv = hr[r * INC + k];
            s1r[r] = fmaf(hv, wa1v, s1r[r]);
            s2r[r] = fmaf(hv, wa2v, s2r[r]);
        }
    }
    #pragma unroll
    for (int r = 0; r < 4; ++r) {
        float s1 = s1r[r], s2 = s2r[r];
        #pragma unroll
        for (int off = 32; off; off >>= 1) {
            s1 += __shfl_xor(s1, off, 64);
            s2 += __shfl_xor(s2, off, 64);
        }
        if (lane == 0) { Wh1[r0 + w * 4 + r] = s1; Wh2[r0 + w * 4 + r] = s2; }
    }
    wt[c][w * 4 + 0] = f2bf(acc0);
    wt[c][w * 4 + 1] = f2bf(acc1);
    wt[c][w * 4 + 2] = f2bf(acc2);
    wt[c][w * 4 + 3] = f2bf(acc3);
    __syncthreads();
    // WhTf frag layout: base (( (j>>5)*4 + (c>>4) )<<9) + ( ((j>>3)&3)*16 + (c&15) )*8 + (j&7)
    if (t < 128) {
        int m = t & 15, ct = (t >> 4) & 3, oct = t >> 6;
        int Kb = r0 >> 5;
        int qh = (r0 >> 3) & 3;              // 0 or 2
        int lanef = (qh + oct) * 16 + m;
        int cidx = ct * 16 + m;
        ushort4 v0, v1;
        v0.x = wt[cidx][oct * 8 + 0]; v0.y = wt[cidx][oct * 8 + 1];
        v0.z = wt[cidx][oct * 8 + 2]; v0.w = wt[cidx][oct * 8 + 3];
        v1.x = wt[cidx][oct * 8 + 4]; v1.y = wt[cidx][oct * 8 + 5];
        v1.z = wt[cidx][oct * 8 + 6]; v1.w = wt[cidx][oct * 8 + 7];
        unsigned short* dst = WhTf + (((size_t)(Kb * 4 + ct)) << 9) + lanef * 8;
        *reinterpret_cast<ushort4*>(dst)     = v0;
        *reinterpret_cast<ushort4*>(dst + 4) = v1;
    }
}

// K2: M = max(Wh2)
__global__ void gat_k2(const float* __restrict__ Wh2, float* __restrict__ M) {
    __shared__ float red[16];
    int t = threadIdx.x;  // 1024
    float4 v0 = *reinterpret_cast<const float4*>(Wh2 + t * 4);
    float4 v1 = *reinterpret_cast<const float4*>(Wh2 + 4096 + t * 4);
    float m = fmaxf(fmaxf(fmaxf(v0.x, v0.y), fmaxf(v0.z, v0.w)),
                    fmaxf(fmaxf(v1.x, v1.y), fmaxf(v1.z, v1.w)));
    #pragma unroll
    for (int off = 32; off; off >>= 1) m = fmaxf(m, __shfl_xor(m, off, 64));
    if ((t & 63) == 0) red[t >> 6] = m;
    __syncthreads();
    if (t == 0) {
        float mm = red[0];
        #pragma unroll
        for (int i = 1; i < 16; ++i) mm = fmaxf(mm, red[i]);
        *M = mm;
    }
}

// K3: grid (512, JSPLIT) x 256 threads; 16 rows/block, 2048-j slice/block.
// 8 blocks/CU resident -> 32 waves/CU. Writes partial (pacc, pl).
__global__ __launch_bounds__(256, 8) void gat_k3(
        const int* __restrict__ adj, const unsigned short* __restrict__ WhTf,
        const float* __restrict__ Wh1, const float* __restrict__ Wh2,
        const float* __restrict__ Mp, float* __restrict__ pacc,
        float* __restrict__ pl) {
    __shared__ float accs[4][16 * OUTC]; // 16 KB
    __shared__ float ls[4][16];
    const int r0 = blockIdx.x * 16;
    const int split = blockIdx.y;
    const int jbase = split * 64;        // in 32-j tile units
    const int t = threadIdx.x;
    const int w = t >> 6, lane = t & 63;
    const int m = lane & 15, q = lane >> 4;
    const int qo = q * 8;
    const int row = r0 + m;
    const float wh1 = Wh1[row];
    const float Mv = *Mp;
    const float sM = wh1 + Mv;
    const float mhat = fmaxf(sM, 0.5f * sM);   // leaky(wh1 + max Wh2) >= row max
    const float mh2 = mhat * LOG2E;
    const int* __restrict__ arow = adj + (size_t)row * NN;
    f32x4 acc[4] = {{0,0,0,0},{0,0,0,0},{0,0,0,0},{0,0,0,0}};
    float lpart = 0.f;

    // software pipeline: adj prefetched 2 iterations ahead
    const int jt0 = jbase + w;
    int4 c0 = *reinterpret_cast<const int4*>(arow + (size_t)jt0 * 32 + qo);
    int4 c1 = *reinterpret_cast<const int4*>(arow + (size_t)jt0 * 32 + qo + 4);
    int4 d0 = *reinterpret_cast<const int4*>(arow + (size_t)(jt0 + 4) * 32 + qo);
    int4 d1 = *reinterpret_cast<const int4*>(arow + (size_t)(jt0 + 4) * 32 + qo + 4);

    #pragma unroll 2
    for (int i = 0; i < 16; ++i) {
        const int jt = jt0 + i * 4;
        // 1) B-fragments (L2-hot, fully coalesced 16 B/lane)
        const unsigned short* fb = WhTf + (size_t)jt * 2048 + lane * 8;
        bf16x8 bv0 = *reinterpret_cast<const bf16x8*>(fb);
        bf16x8 bv1 = *reinterpret_cast<const bf16x8*>(fb + 512);
        bf16x8 bv2 = *reinterpret_cast<const bf16x8*>(fb + 1024);
        bf16x8 bv3 = *reinterpret_cast<const bf16x8*>(fb + 1536);
        // 2) Wh2 (L1-hot)
        const int jb = jt * 32 + qo;
        float4 s0 = *reinterpret_cast<const float4*>(Wh2 + jb);
        float4 s1 = *reinterpret_cast<const float4*>(Wh2 + jb + 4);
        // 3) adj prefetch for i+2 (issued last -> stays in flight past the s-wait)
        const int jn = (i < 14) ? (jt + 8) : jt0;
        const int* __restrict__ an = arow + (size_t)jn * 32 + qo;
        int4 e0 = *reinterpret_cast<const int4*>(an);
        int4 e1 = *reinterpret_cast<const int4*>(an + 4);
        // 4) p from current adj (loaded 2 iters ago) + Wh2
        float sv[8] = {s0.x, s0.y, s0.z, s0.w, s1.x, s1.y, s1.z, s1.w};
        int   av[8] = {c0.x, c0.y, c0.z, c0.w, c1.x, c1.y, c1.z, c1.w};
        float p[8];
        #pragma unroll
        for (int e = 0; e < 8; ++e) {
            float s  = wh1 + sv[e];
            float lk = fmaxf(s, 0.5f * s);        // leakyrelu(0.5)
            float ar = fmaf(lk, LOG2E, -mh2);
            float pe = EXP2(ar);
            p[e] = (av[e] > 0) ? pe : 0.f;
        }
        lpart += ((p[0] + p[1]) + (p[2] + p[3])) + ((p[4] + p[5]) + (p[6] + p[7]));
        bf16x8 af;
        #pragma unroll
        for (int e = 0; e < 8; ++e) af[e] = (__bf16)p[e];
        // 5) MFMA (waits bv only; adj prefetch stays outstanding)
        acc[0] = __builtin_amdgcn_mfma_f32_16x16x32_bf16(af, bv0, acc[0], 0, 0, 0);
        acc[1] = __builtin_amdgcn_mfma_f32_16x16x32_bf16(af, bv1, acc[1], 0, 0, 0);
        acc[2] = __builtin_amdgcn_mfma_f32_16x16x32_bf16(af, bv2, acc[2], 0, 0, 0);
        acc[3] = __builtin_amdgcn_mfma_f32_16x16x32_bf16(af, bv3, acc[3], 0, 0, 0);
        c0 = d0; c1 = d1; d0 = e0; d1 = e1;
    }
    // dump accumulators: C/D layout col=lane&15, row=q*4+reg
    #pragma unroll
    for (int ct = 0; ct < 4; ++ct)
        #pragma unroll
        for (int r = 0; r < 4; ++r)
            accs[w][(q * 4 + r) * OUTC + ct * 16 + m] = acc[ct][r];
    float l = lpart;
    l += __shfl_xor(l, 16, 64);
    l += __shfl_xor(l, 32, 64);
    if (lane < 16) ls[w][lane] = l;
    __syncthreads();
    float* pa = pacc + ((size_t)split * NN + r0) * OUTC;
    #pragma unroll
    for (int e = t; e < 16 * OUTC; e += 256) {
        int rr = e >> 6, cc = e & 63;
        float s = (accs[0][e] + accs[1][e]) + (accs[2][e] + accs[3][e]);
        pa[e] = s;
        if (cc == 0) pl[(size_t)split * NN + r0 + rr] =
            (ls[0][rr] + ls[1][rr]) + (ls[2][rr] + ls[3][rr]);
    }
}

// K4: combine JSPLIT partials, divide by l, relu. 512 blocks x 256 threads, float4.
__global__ __launch_bounds__(256) void gat_k4(
        const float* __restrict__ pacc, const float* __restrict__ pl,
        float* __restrict__ out) {
    const int idx4 = (blockIdx.x * 256 + threadIdx.x) * 4;
    const int row = idx4 >> 6;
    f32x4 s = {0.f, 0.f, 0.f, 0.f};
    float l = 0.f;
    #pragma unroll
    for (int sp = 0; sp < JSPLIT; ++sp) {
        f32x4 v = *reinterpret_cast<const f32x4*>(pacc + (size_t)sp * NN * OUTC + idx4);
        s += v;
        l += pl[(size_t)sp * NN + row];
    }
    float rl = 1.0f / l;
    f32x4 o;
    #pragma unroll
    for (int e = 0; e < 4; ++e) {
        float v = s[e] * rl;
        o[e] = v > 0.f ? v : 0.f;
    }
    *reinterpret_cast<f32x4*>(out + idx4) = o;
}

extern "C" void kernel_launch(void* const* d_in, const int* in_sizes, int n_in,
                              void* d_out, int out_size, void* d_ws, size_t ws_size,
                              hipStream_t stream) {
    const float* h   = (const float*)d_in[0];
    const int*   adj = (const int*)d_in[1];
    const float* W   = (const float*)d_in[2];
    const float* a   = (const float*)d_in[3];
    float* out = (float*)d_out;

    char* base = (char*)d_ws;
    float* Wh1 = (float*)(base);                 // 8192 f @ 0
    float* Wh2 = (float*)(base + 32768);         // 8192 f @ 32 KB
    float* Mp  = (float*)(base + 65536);         // 1 f
    unsigned short* WhTf = (unsigned short*)(base + 69632); // 64*8192 bf16 = 1 MB
    float* pacc = (float*)(base + 2166784);      // JSPLIT*8192*64 f = 8 MB
    float* pl   = (float*)(base + 2166784 + (size_t)JSPLIT * NN * OUTC * 4); // 128 KB

    gat_k1<<<NN / 16, 256, 0, stream>>>(h, W, a, WhTf, Wh1, Wh2);
    gat_k2<<<1, 1024, 0, stream>>>(Wh2, Mp);
    gat_k3<<<dim3(NN / 16, JSPLIT), 256, 0, stream>>>(adj, WhTf, Wh1, Wh2, Mp, pacc, pl);
    gat_k4<<<NN * OUTC / 1024, 256, 0, stream>>>(pacc, pl, out);
}

// Round 5
// 422.570 us; speedup vs baseline: 1.1382x; 1.0090x over previous
//
#include <hip/hip_runtime.h>
#include <stdint.h>

#define NN 8192
#define INC 256
#define OUTC 64
#define LOG2E 1.4426950408889634f
#define JSPLIT 4

typedef __bf16 bf16x8 __attribute__((ext_vector_type(8)));
typedef float f32x4 __attribute__((ext_vector_type(4)));

__device__ __forceinline__ unsigned short f2bf(float x) {
    union { float f; unsigned u; } v; v.f = x;
    unsigned u = v.u;
    u += 0x7fffu + ((u >> 16) & 1u);   // RNE, inputs never NaN
    return (unsigned short)(u >> 16);
}

#if __has_builtin(__builtin_amdgcn_exp2f)
#define EXP2(x) __builtin_amdgcn_exp2f(x)
#else
#define EXP2(x) exp2f(x)
#endif

// PACK: adj (256 MB int32 0/1) -> maskT (8 MB bits), transposed for K3.
// One block per row; lane tx covers j-word tx (32 j). Lane reads 128 B
// contiguous (wave covers the full 32 KB row); writes coalesce per-block
// into maskT[word*NN + row].
__global__ __launch_bounds__(256) void gat_pack(
        const int* __restrict__ adj, uint32_t* __restrict__ maskT) {
    const int row = blockIdx.x;
    const int tx  = threadIdx.x;
    const int* p = adj + (size_t)row * NN + tx * 32;
    uint32_t m = 0;
    #pragma unroll
    for (int k = 0; k < 8; ++k) {
        int4 v = *reinterpret_cast<const int4*>(p + k * 4);
        m |= (uint32_t)v.x << (k * 4 + 0);
        m |= (uint32_t)v.y << (k * 4 + 1);
        m |= (uint32_t)v.z << (k * 4 + 2);
        m |= (uint32_t)v.w << (k * 4 + 3);
    }
    maskT[(size_t)tx * NN + row] = m;
}

// K1: per 16-row block: Wh -> WhTf (MFMA-B-frag interleaved bf16) + Wh1[i] + Wh2[i]
__global__ __launch_bounds__(256) void gat_k1(
        const float* __restrict__ h, const float* __restrict__ W,
        const float* __restrict__ a,
        unsigned short* __restrict__ WhTf, float* __restrict__ Wh1,
        float* __restrict__ Wh2) {
    __shared__ float Ws[256 * 65];          // 65 KB, padded (conflict-free both phases)
    __shared__ float hs[16 * INC];          // 16 KB
    __shared__ float Wa1s[256], Wa2s[256], as_[128];
    __shared__ unsigned short wt[OUTC][16]; // transpose buffer
    const int r0 = blockIdx.x * 16;
    const int t  = threadIdx.x;
    if (t < 128) as_[t] = a[t];
    #pragma unroll
    for (int it = 0; it < 16; ++it) {
        int idx = it * 1024 + t * 4;        // flat index into W
        float4 v = *reinterpret_cast<const float4*>(W + idx);
        int k = idx >> 6, c = idx & 63;
        float* dst = &Ws[k * 65 + c];
        dst[0] = v.x; dst[1] = v.y; dst[2] = v.z; dst[3] = v.w;
    }
    #pragma unroll
    for (int it = 0; it < 4; ++it) {
        int idx = it * 1024 + t * 4;
        float4 v = *reinterpret_cast<const float4*>(h + (size_t)r0 * INC + idx);
        hs[idx] = v.x; hs[idx + 1] = v.y; hs[idx + 2] = v.z; hs[idx + 3] = v.w;
    }
    __syncthreads();
    {
        float s1 = 0.f, s2 = 0.f;
        #pragma unroll 8
        for (int c = 0; c < OUTC; ++c) {
            float w = Ws[t * 65 + c];
            s1 = fmaf(w, as_[c], s1);
            s2 = fmaf(w, as_[OUTC + c], s2);
        }
        Wa1s[t] = s1; Wa2s[t] = s2;
    }
    __syncthreads();
    const int w = t >> 6, lane = t & 63;
    const int c = lane;
    const float* hr = &hs[w * 4 * INC];
    float acc0 = 0.f, acc1 = 0.f, acc2 = 0.f, acc3 = 0.f;
    #pragma unroll 8
    for (int k = 0; k < INC; ++k) {
        float wv = Ws[k * 65 + c];
        acc0 = fmaf(hr[k],           wv, acc0);
        acc1 = fmaf(hr[INC + k],     wv, acc1);
        acc2 = fmaf(hr[2 * INC + k], wv, acc2);
        acc3 = fmaf(hr[3 * INC + k], wv, acc3);
    }
    float s1r[4] = {0.f, 0.f, 0.f, 0.f}, s2r[4] = {0.f, 0.f, 0.f, 0.f};
    #pragma unroll
    for (int kk = 0; kk < 4; ++kk) {
        int k = kk * 64 + lane;
        float wa1v = Wa1s[k], wa2v = Wa2s[k];
        #pragma unroll
        for (int r = 0; r < 4; ++r) {
            float hv = hr[r * INC + k];
            s1r[r] = fmaf(hv, wa1v, s1r[r]);
            s2r[r] = fmaf(hv, wa2v, s2r[r]);
        }
    }
    #pragma unroll
    for (int r = 0; r < 4; ++r) {
        float s1 = s1r[r], s2 = s2r[r];
        #pragma unroll
        for (int off = 32; off; off >>= 1) {
            s1 += __shfl_xor(s1, off, 64);
            s2 += __shfl_xor(s2, off, 64);
        }
        if (lane == 0) { Wh1[r0 + w * 4 + r] = s1; Wh2[r0 + w * 4 + r] = s2; }
    }
    wt[c][w * 4 + 0] = f2bf(acc0);
    wt[c][w * 4 + 1] = f2bf(acc1);
    wt[c][w * 4 + 2] = f2bf(acc2);
    wt[c][w * 4 + 3] = f2bf(acc3);
    __syncthreads();
    // WhTf frag layout: base (( (j>>5)*4 + (c>>4) )<<9) + ( ((j>>3)&3)*16 + (c&15) )*8 + (j&7)
    if (t < 128) {
        int m = t & 15, ct = (t >> 4) & 3, oct = t >> 6;
        int Kb = r0 >> 5;
        int qh = (r0 >> 3) & 3;              // 0 or 2
        int lanef = (qh + oct) * 16 + m;
        int cidx = ct * 16 + m;
        ushort4 v0, v1;
        v0.x = wt[cidx][oct * 8 + 0]; v0.y = wt[cidx][oct * 8 + 1];
        v0.z = wt[cidx][oct * 8 + 2]; v0.w = wt[cidx][oct * 8 + 3];
        v1.x = wt[cidx][oct * 8 + 4]; v1.y = wt[cidx][oct * 8 + 5];
        v1.z = wt[cidx][oct * 8 + 6]; v1.w = wt[cidx][oct * 8 + 7];
        unsigned short* dst = WhTf + (((size_t)(Kb * 4 + ct)) << 9) + lanef * 8;
        *reinterpret_cast<ushort4*>(dst)     = v0;
        *reinterpret_cast<ushort4*>(dst + 4) = v1;
    }
}

// K2: M = max(Wh2)
__global__ void gat_k2(const float* __restrict__ Wh2, float* __restrict__ M) {
    __shared__ float red[16];
    int t = threadIdx.x;  // 1024
    float4 v0 = *reinterpret_cast<const float4*>(Wh2 + t * 4);
    float4 v1 = *reinterpret_cast<const float4*>(Wh2 + 4096 + t * 4);
    float m = fmaxf(fmaxf(fmaxf(v0.x, v0.y), fmaxf(v0.z, v0.w)),
                    fmaxf(fmaxf(v1.x, v1.y), fmaxf(v1.z, v1.w)));
    #pragma unroll
    for (int off = 32; off; off >>= 1) m = fmaxf(m, __shfl_xor(m, off, 64));
    if ((t & 63) == 0) red[t >> 6] = m;
    __syncthreads();
    if (t == 0) {
        float mm = red[0];
        #pragma unroll
        for (int i = 1; i < 16; ++i) mm = fmaxf(mm, red[i]);
        *M = mm;
    }
}

// K3: grid (512, JSPLIT) x 256 threads; 16 rows/block, 2048-j slice/block.
// adj replaced by L2-resident bitmask: 1 dword/lane/iter. Writes partial (pacc, pl).
__global__ __launch_bounds__(256, 6) void gat_k3(
        const uint32_t* __restrict__ maskT, const unsigned short* __restrict__ WhTf,
        const float* __restrict__ Wh1, const float* __restrict__ Wh2,
        const float* __restrict__ Mp, float* __restrict__ pacc,
        float* __restrict__ pl) {
    __shared__ float accs[4][16 * OUTC]; // 16 KB
    __shared__ float ls[4][16];
    const int r0 = blockIdx.x * 16;
    const int split = blockIdx.y;
    const int t = threadIdx.x;
    const int w = t >> 6, lane = t & 63;
    const int m = lane & 15, q = lane >> 4;
    const int qo = q * 8;
    const int row = r0 + m;
    const float wh1 = Wh1[row];
    const float Mv = *Mp;
    const float sM = wh1 + Mv;
    const float mhat = fmaxf(sM, 0.5f * sM);   // leaky(wh1 + max Wh2) >= row max
    const float mh2 = mhat * LOG2E;
    f32x4 acc[4] = {{0,0,0,0},{0,0,0,0},{0,0,0,0},{0,0,0,0}};
    float lpart = 0.f;
    const int jt0 = split * 64 + w;            // 32-j tiles, stride 4, 16 iters

    #pragma unroll 2
    for (int i = 0; i < 16; ++i) {
        const int jt = jt0 + i * 4;
        // mask word: 16 consecutive dwords, broadcast across quads (L2-hot)
        uint32_t mk = maskT[(size_t)jt * NN + row];
        // B-fragments (L2-hot, fully coalesced 16 B/lane)
        const unsigned short* fb = WhTf + (size_t)jt * 2048 + lane * 8;
        bf16x8 bv0 = *reinterpret_cast<const bf16x8*>(fb);
        bf16x8 bv1 = *reinterpret_cast<const bf16x8*>(fb + 512);
        bf16x8 bv2 = *reinterpret_cast<const bf16x8*>(fb + 1024);
        bf16x8 bv3 = *reinterpret_cast<const bf16x8*>(fb + 1536);
        // Wh2 (L1/L2-hot)
        const int jb = jt * 32 + qo;
        float4 s0 = *reinterpret_cast<const float4*>(Wh2 + jb);
        float4 s1 = *reinterpret_cast<const float4*>(Wh2 + jb + 4);
        float sv[8] = {s0.x, s0.y, s0.z, s0.w, s1.x, s1.y, s1.z, s1.w};
        const uint32_t mq = mk >> qo;
        float p[8];
        #pragma unroll
        for (int e = 0; e < 8; ++e) {
            float s  = wh1 + sv[e];
            float lk = fmaxf(s, 0.5f * s);        // leakyrelu(0.5)
            float ar = fmaf(lk, LOG2E, -mh2);
            float pe = EXP2(ar);
            p[e] = ((mq >> e) & 1u) ? pe : 0.f;
        }
        lpart += ((p[0] + p[1]) + (p[2] + p[3])) + ((p[4] + p[5]) + (p[6] + p[7]));
        bf16x8 af;
        #pragma unroll
        for (int e = 0; e < 8; ++e) af[e] = (__bf16)p[e];
        acc[0] = __builtin_amdgcn_mfma_f32_16x16x32_bf16(af, bv0, acc[0], 0, 0, 0);
        acc[1] = __builtin_amdgcn_mfma_f32_16x16x32_bf16(af, bv1, acc[1], 0, 0, 0);
        acc[2] = __builtin_amdgcn_mfma_f32_16x16x32_bf16(af, bv2, acc[2], 0, 0, 0);
        acc[3] = __builtin_amdgcn_mfma_f32_16x16x32_bf16(af, bv3, acc[3], 0, 0, 0);
    }
    // dump accumulators: C/D layout col=lane&15, row=q*4+reg
    #pragma unroll
    for (int ct = 0; ct < 4; ++ct)
        #pragma unroll
        for (int r = 0; r < 4; ++r)
            accs[w][(q * 4 + r) * OUTC + ct * 16 + m] = acc[ct][r];
    float l = lpart;
    l += __shfl_xor(l, 16, 64);
    l += __shfl_xor(l, 32, 64);
    if (lane < 16) ls[w][lane] = l;
    __syncthreads();
    float* pa = pacc + ((size_t)split * NN + r0) * OUTC;
    #pragma unroll
    for (int e = t; e < 16 * OUTC; e += 256) {
        int rr = e >> 6, cc = e & 63;
        float s = (accs[0][e] + accs[1][e]) + (accs[2][e] + accs[3][e]);
        pa[e] = s;
        if (cc == 0) pl[(size_t)split * NN + r0 + rr] =
            (ls[0][rr] + ls[1][rr]) + (ls[2][rr] + ls[3][rr]);
    }
}

// K4: combine JSPLIT partials, divide by l, relu. 512 blocks x 256 threads, float4.
__global__ __launch_bounds__(256) void gat_k4(
        const float* __restrict__ pacc, const float* __restrict__ pl,
        float* __restrict__ out) {
    const int idx4 = (blockIdx.x * 256 + threadIdx.x) * 4;
    const int row = idx4 >> 6;
    f32x4 s = {0.f, 0.f, 0.f, 0.f};
    float l = 0.f;
    #pragma unroll
    for (int sp = 0; sp < JSPLIT; ++sp) {
        f32x4 v = *reinterpret_cast<const f32x4*>(pacc + (size_t)sp * NN * OUTC + idx4);
        s += v;
        l += pl[(size_t)sp * NN + row];
    }
    float rl = 1.0f / l;
    f32x4 o;
    #pragma unroll
    for (int e = 0; e < 4; ++e) {
        float v = s[e] * rl;
        o[e] = v > 0.f ? v : 0.f;
    }
    *reinterpret_cast<f32x4*>(out + idx4) = o;
}

extern "C" void kernel_launch(void* const* d_in, const int* in_sizes, int n_in,
                              void* d_out, int out_size, void* d_ws, size_t ws_size,
                              hipStream_t stream) {
    const float* h   = (const float*)d_in[0];
    const int*   adj = (const int*)d_in[1];
    const float* W   = (const float*)d_in[2];
    const float* a   = (const float*)d_in[3];
    float* out = (float*)d_out;

    char* base = (char*)d_ws;
    float* Wh1 = (float*)(base);                 // 8192 f @ 0
    float* Wh2 = (float*)(base + 32768);         // 8192 f @ 32 KB
    float* Mp  = (float*)(base + 65536);         // 1 f
    unsigned short* WhTf = (unsigned short*)(base + 69632); // 64*8192 bf16 = 1 MB
    float* pacc = (float*)(base + 2166784);      // JSPLIT*8192*64 f = 8 MB
    float* pl   = (float*)(base + 2166784 + (size_t)JSPLIT * NN * OUTC * 4); // 128 KB
    uint32_t* maskT = (uint32_t*)(base + 10686464); // 256*8192 u32 = 8 MB

    gat_pack<<<NN, 256, 0, stream>>>(adj, maskT);
    gat_k1<<<NN / 16, 256, 0, stream>>>(h, W, a, WhTf, Wh1, Wh2);
    gat_k2<<<1, 1024, 0, stream>>>(Wh2, Mp);
    gat_k3<<<dim3(NN / 16, JSPLIT), 256, 0, stream>>>(maskT, WhTf, Wh1, Wh2, Mp, pacc, pl);
    gat_k4<<<NN * OUTC / 1024, 256, 0, stream>>>(pacc, pl, out);
}